// Round 17
// baseline (144.784 us; speedup 1.0000x reference)
//
#include <hip/hip_runtime.h>

#define IN_DIM 256
#define HC     128   // H*C
#define NHEAD  4
#define NEG    0.2f
#define BKT    1024  // dsts per bucket
#define NBMAX  128   // max buckets (n <= 131072)
#define EPT2   8     // edges per thread (fused 512-thr scatter)
#define BE     4096  // edges per block
#define PACKB  16    // pack_w blocks in fused K1
#define NGEMM  512   // persistent gemm blocks in K3

typedef __attribute__((ext_vector_type(8))) short short8v;
typedef __attribute__((ext_vector_type(4))) float f32x4;
typedef __attribute__((ext_vector_type(2))) float f32x2;
typedef __attribute__((ext_vector_type(4))) unsigned short ushort4v;

__device__ __forceinline__ unsigned short bf16_rn(float f) {
    unsigned u = __builtin_bit_cast(unsigned, f);
    return (unsigned short)((u + 0x7fffu + ((u >> 16) & 1u)) >> 16);
}
__device__ __forceinline__ float bf16_lo(unsigned v) {
    return __builtin_bit_cast(float, v << 16);
}
__device__ __forceinline__ float bf16_hi(unsigned v) {
    return __builtin_bit_cast(float, v & 0xffff0000u);
}
__device__ __forceinline__ float fast_tanh(float x) {
    float t = __expf(2.f * x);
    return fmaf(-2.f, __builtin_amdgcn_rcpf(t + 1.f), 1.f);
}
__device__ __forceinline__ float lrelu(float e) {
    return fmaxf(e, NEG * e);
}

// ---------------- K1: pack W (blocks 0..15)  ||  bucket histogram (rest) ----------------
__global__ __launch_bounds__(256) void pack_hist_kernel(const float* __restrict__ W,
                                                        unsigned short* __restrict__ w_hi,
                                                        const int* __restrict__ ei,
                                                        int* __restrict__ bucket_cnt,
                                                        int E, int nb) {
    __shared__ int lh[NBMAX];
    int tid = threadIdx.x;
    if (blockIdx.x < PACKB) {
        int t = blockIdx.x * 256 + tid;
        int l  = t & 63;
        int ct = (t >> 6) & 7;
        int s  = t >> 9;
        int kbase = s * 32 + (l >> 4) * 8;
        int col   = ct * 16 + (l & 15);
        size_t base = (size_t)t * 8;
#pragma unroll
        for (int e = 0; e < 8; ++e)
            w_hi[base + e] = bf16_rn(W[(size_t)(kbase + e) * HC + col]);
        return;
    }
    if (tid < NBMAX) lh[tid] = 0;
    __syncthreads();
    int base = (blockIdx.x - PACKB) * BE;
#pragma unroll
    for (int i = 0; i < 16; ++i) {
        int e = base + i * 256 + tid;
        if (e < E) atomicAdd(&lh[ei[E + e] >> 10], 1);
    }
    __syncthreads();
    if (tid < nb && lh[tid]) atomicAdd(&bucket_cnt[tid], lh[tid]);
}

// ---------------- K2: exclusive scan of bucket counts ----------------
__global__ __launch_bounds__(128) void bucket_scan_kernel(const int* __restrict__ bucket_cnt,
                                                          int* __restrict__ bucket_base,
                                                          int* __restrict__ bucket_cursor,
                                                          int nb) {
    __shared__ int ws0[1];
    int t = threadIdx.x;
    int v = (t < nb) ? bucket_cnt[t] : 0;
    int lane = t & 63, wd = t >> 6;
    int x = v;
#pragma unroll
    for (int off = 1; off < 64; off <<= 1) {
        int y = __shfl_up(x, off);
        if (lane >= off) x += y;
    }
    if (wd == 0 && lane == 63) ws0[0] = x;
    __syncthreads();
    int wo = wd ? ws0[0] : 0;
    int excl = wo + x - v;
    if (t < nb) { bucket_base[t] = excl; bucket_cursor[t] = excl; }
    if (t == 127) bucket_base[nb] = wo + x;   // total = E
}

// ---------------- K3: bucket scatter (blocks < nblkE)  ||  persistent GEMM (rest) ------
union KSmem {
    struct {
        unsigned short s_bf[64 * 256];   // 32 KB swizzled A tile
        float pS[64][4];
        float pD[64][4];
    } g;
    struct {
        int lh[NBMAX];
        int lofs[NBMAX];
        int gofs[NBMAX];
        int ws0;
        unsigned buf[BE];                // 16 KB
    } s;
};

__global__ __launch_bounds__(512, 2) void scatter_gemm_kernel(const int* __restrict__ ei,
                                                              int* __restrict__ bucket_cursor,
                                                              unsigned* __restrict__ bucket_data,
                                                              int E, int nb, int nblkE,
                                                              const float* __restrict__ x,
                                                              const unsigned short* __restrict__ w_hi,
                                                              const float* __restrict__ a_src,
                                                              const float* __restrict__ a_dst,
                                                              unsigned short* __restrict__ h_bf,
                                                              float* __restrict__ alpha_s,
                                                              float* __restrict__ alpha_d, int n) {
    __shared__ KSmem sm;
    const int tid = threadIdx.x;

    if ((int)blockIdx.x < nblkE) {
        // ---------------- scatter path (512 threads, EPT2=8) ----------------
        if (tid < NBMAX) sm.s.lh[tid] = 0;
        __syncthreads();

        int base = blockIdx.x * BE;
        int bb[EPT2]; unsigned wv[EPT2]; int rr[EPT2];
#pragma unroll
        for (int i = 0; i < EPT2; ++i) {
            int e = base + i * 512 + tid;
            if (e < E) {
                int src = ei[e];
                int dst = ei[E + e];
                bb[i] = dst >> 10;
                wv[i] = (unsigned)src | ((unsigned)(dst & 1023) << 17);
                rr[i] = atomicAdd(&sm.s.lh[bb[i]], 1);
            } else bb[i] = -1;
        }
        __syncthreads();

        int lane = tid & 63, wd = tid >> 6;
        int v_ = 0, x_ = 0;
        if (tid < NBMAX) {
            v_ = sm.s.lh[tid]; x_ = v_;
#pragma unroll
            for (int off = 1; off < 64; off <<= 1) {
                int y = __shfl_up(x_, off);
                if (lane >= off) x_ += y;
            }
            if (wd == 0 && lane == 63) sm.s.ws0 = x_;
        }
        __syncthreads();
        if (tid < NBMAX) {
            int wo = wd ? sm.s.ws0 : 0;
            sm.s.lofs[tid] = wo + x_ - v_;
        }
        __syncthreads();

#pragma unroll
        for (int i = 0; i < EPT2; ++i)
            if (bb[i] >= 0) sm.s.buf[sm.s.lofs[bb[i]] + rr[i]] = wv[i];
        if (tid < nb) sm.s.gofs[tid] = sm.s.lh[tid] ? atomicAdd(&bucket_cursor[tid], sm.s.lh[tid]) : 0;
        __syncthreads();

        int wid = tid >> 6;
        for (int bk = wid; bk < nb; bk += 8) {
            int lo = sm.s.lofs[bk], cnt = sm.s.lh[bk], g = sm.s.gofs[bk];
            for (int j = lane; j < cnt; j += 64)
                bucket_data[g + j] = sm.s.buf[lo + j];
        }
        return;
    }

    // ---------------- persistent GEMM path: B-fragments register-resident ----------------
    const int l   = tid & 63;
    const int wv_ = tid >> 6;
    const int ct_g = wv_ & 3;
    const int rt_g = wv_ >> 2;
    const int rrow = l & 15;
    const int kq   = l >> 4;

    // load ALL 16 B-fragments once per block (static indices -> registers)
    short8v bhall[8][2];
#pragma unroll
    for (int s = 0; s < 8; ++s)
#pragma unroll
        for (int c = 0; c < 2; ++c)
            bhall[s][c] = *reinterpret_cast<const short8v*>(
                w_hi + ((size_t)(s * 8 + ct_g * 2 + c) * 64 + l) * 8);

    const f32x4* x4 = reinterpret_cast<const f32x4*>(x);

    for (int gidx = (int)blockIdx.x - nblkE; gidx * 64 < n; gidx += NGEMM) {
        const int row0 = gidx * 64;

        // stage + convert x tile -> swizzled LDS
#pragma unroll
        for (int i = 0; i < 8; ++i) {
            int row = i * 8 + wv_;
            int c4  = l;
            f32x4 v = (f32x4){0.f, 0.f, 0.f, 0.f};
            if (row0 + row < n) v = __builtin_nontemporal_load(&x4[(size_t)(row0 + row) * 64 + c4]);
            ushort4v b;
            b[0] = bf16_rn(v[0]); b[1] = bf16_rn(v[1]);
            b[2] = bf16_rn(v[2]); b[3] = bf16_rn(v[3]);
            int slot = (c4 >> 1) ^ (row & 7);
            int uidx = row * 256 + (slot << 3) + ((c4 & 1) << 2);
            *reinterpret_cast<ushort4v*>(&sm.g.s_bf[uidx]) = b;
        }
        __syncthreads();

        f32x4 acc[2][2];
#pragma unroll
        for (int a = 0; a < 2; ++a)
#pragma unroll
            for (int b2 = 0; b2 < 2; ++b2) acc[a][b2] = (f32x4){0.f, 0.f, 0.f, 0.f};

#pragma unroll
        for (int s = 0; s < 8; ++s) {
#pragma unroll
            for (int r = 0; r < 2; ++r) {
                int arow = rt_g * 32 + r * 16 + rrow;
                int c16  = kq + s * 4;
                int uidx = arow * 256 + ((c16 ^ (arow & 7)) << 3);
                short8v ah = *reinterpret_cast<const short8v*>(&sm.g.s_bf[uidx]);
#pragma unroll
                for (int c = 0; c < 2; ++c)
                    acc[r][c] = __builtin_amdgcn_mfma_f32_16x16x32_bf16(ah, bhall[s][c], acc[r][c], 0, 0, 0);
            }
        }

        // epilogue 1: h as bf16
#pragma unroll
        for (int r = 0; r < 2; ++r) {
#pragma unroll
            for (int c = 0; c < 2; ++c) {
                int col = (ct_g * 2 + c) * 16 + (l & 15);
#pragma unroll
                for (int q = 0; q < 4; ++q) {
                    int row = row0 + rt_g * 32 + r * 16 + (l >> 4) * 4 + q;
                    if (row < n) h_bf[(size_t)row * HC + col] = bf16_rn(acc[r][c][q]);
                }
            }
        }

        // epilogue 2: alpha logits
        float asc[2], adc[2];
#pragma unroll
        for (int c = 0; c < 2; ++c) {
            int col = (ct_g * 2 + c) * 16 + (l & 15);
            asc[c] = a_src[col];
            adc[c] = a_dst[col];
        }
#pragma unroll
        for (int r = 0; r < 2; ++r) {
#pragma unroll
            for (int q = 0; q < 4; ++q) {
                float vS = acc[r][0][q] * asc[0] + acc[r][1][q] * asc[1];
                float vD = acc[r][0][q] * adc[0] + acc[r][1][q] * adc[1];
#pragma unroll
                for (int m = 1; m < 16; m <<= 1) {
                    vS += __shfl_xor(vS, m);
                    vD += __shfl_xor(vD, m);
                }
                if ((l & 15) == 0) {
                    int rl = rt_g * 32 + r * 16 + (l >> 4) * 4 + q;
                    sm.g.pS[rl][ct_g] = vS;
                    sm.g.pD[rl][ct_g] = vD;
                }
            }
        }
        __syncthreads();
        if (tid < 256) {
            int rl = tid >> 2, h = tid & 3;
            int row = row0 + rl;
            if (row < n) {
                alpha_s[(size_t)row * 4 + h] = sm.g.pS[rl][h];
                alpha_d[(size_t)row * 4 + h] = sm.g.pD[rl][h];
            }
        }
        __syncthreads();   // pS reads done before next tile's stage/pS writes
    }
}

// ---------------- K4: per-bucket CSR finalize (LDS atomics only) ----------------
__global__ __launch_bounds__(1024) void bucket_build_kernel(const int* __restrict__ bucket_base,
                                                            const unsigned* __restrict__ bucket_data,
                                                            int* __restrict__ deg,
                                                            int* __restrict__ row_start,
                                                            int* __restrict__ csr_src, int n) {
    __shared__ int lc[BKT];
    __shared__ int sc[BKT];
    __shared__ int wsum[16];

    int b = blockIdx.x;
    int base = bucket_base[b];
    int end  = bucket_base[b + 1];
    int t = threadIdx.x;

    lc[t] = 0;
    __syncthreads();
    for (int i = base + t; i < end; i += 1024)
        atomicAdd(&lc[bucket_data[i] >> 17], 1);
    __syncthreads();

    int val = lc[t];
    int lane = t & 63, wd = t >> 6;
    int x = val;
#pragma unroll
    for (int off = 1; off < 64; off <<= 1) {
        int y = __shfl_up(x, off);
        if (lane >= off) x += y;
    }
    if (lane == 63) wsum[wd] = x;
    __syncthreads();
    if (wd == 0 && lane < 16) {
        int y = wsum[lane];
#pragma unroll
        for (int off = 1; off < 16; off <<= 1) {
            int z = __shfl_up(y, off);
            if (lane >= off) y += z;
        }
        wsum[lane] = y;
    }
    __syncthreads();
    int wo = wd ? wsum[wd - 1] : 0;
    int excl = wo + x - val;
    sc[t] = excl;
    int v = b * BKT + t;
    if (v < n) { deg[v] = val; row_start[v] = base + excl; }
    lc[t] = 0;
    __syncthreads();

    for (int i = base + t; i < end; i += 1024) {
        unsigned w = bucket_data[i];
        int d = w >> 17;
        int src = (int)(w & 0x1FFFFu);
        int p = atomicAdd(&lc[d], 1);
        csr_src[base + sc[d] + p] = src;
    }
}

// ---------------- K5: gather — cooperative-load single-pass softmax+PV+tanh ----------
__global__ __launch_bounds__(256, 4) void gather_kernel(const int* __restrict__ row_start,
                                                        const int* __restrict__ deg,
                                                        const int* __restrict__ csr_src,
                                                        const float* __restrict__ alpha_s,
                                                        const float* __restrict__ alpha_d,
                                                        const unsigned short* __restrict__ h_bf,
                                                        const float* __restrict__ bias,
                                                        float* __restrict__ out, int n) {
    int lane = threadIdx.x & 63;
    int wid  = threadIdx.x >> 6;
    int v = blockIdx.x * 4 + wid;
    if (v >= n) return;
    int start = row_start[v];
    int cnt = deg[v];
    int head = lane >> 4;   // output head
    int hc   = lane & 3;    // cooperative head

    const unsigned* hb = reinterpret_cast<const unsigned*>(h_bf);

    float adC = alpha_d[(size_t)v * 4 + hc];
    float asC = alpha_s[(size_t)v * 4 + hc];
    float adH = __shfl(adC, head);
    float asH = __shfl(asC, head);
    float pself = __expf(lrelu(asH + adH));
    unsigned hv0 = hb[((unsigned)v << 6) + lane];
    float s = pself;
    float accx = pself * bf16_lo(hv0);
    float accy = pself * bf16_hi(hv0);

    int j = 0;
    for (; j + 8 <= cnt; j += 8) {
        int cv = csr_src[start + j + (lane & 7)];
        int sj = __shfl(cv, lane >> 2);
        float av = alpha_s[(size_t)sj * 4 + hc];
        float w  = __expf(lrelu(av + adC));
#pragma unroll
        for (int k = 0; k < 8; ++k) {
            int sk   = __shfl(cv, k);
            float wk = __shfl(w, (k << 2) | head);
            unsigned hk = hb[((unsigned)sk << 6) + lane];
            s += wk;
            accx = fmaf(wk, bf16_lo(hk), accx);
            accy = fmaf(wk, bf16_hi(hk), accy);
        }
    }
    if (j + 4 <= cnt) {
        int cv = csr_src[start + j + (lane & 3)];
        int sj = __shfl(cv, lane >> 2);
        float av = alpha_s[(size_t)sj * 4 + hc];
        float w  = __expf(lrelu(av + adC));
#pragma unroll
        for (int k = 0; k < 4; ++k) {
            int sk   = __shfl(cv, k);
            float wk = __shfl(w, (k << 2) | head);
            unsigned hk = hb[((unsigned)sk << 6) + lane];
            s += wk;
            accx = fmaf(wk, bf16_lo(hk), accx);
            accy = fmaf(wk, bf16_hi(hk), accy);
        }
        j += 4;
    }
    for (; j < cnt; ++j) {
        int s0 = csr_src[start + j];
        float a0 = alpha_s[(size_t)s0 * 4 + head];
        unsigned h0 = hb[((unsigned)s0 << 6) + lane];
        float w0 = __expf(lrelu(a0 + adH));
        s += w0;
        accx = fmaf(w0, bf16_lo(h0), accx);
        accy = fmaf(w0, bf16_hi(h0), accy);
    }

    float invH = __builtin_amdgcn_rcpf(s + 1e-16f);
    float2 b = reinterpret_cast<const float2*>(bias)[lane];
    f32x2 o;
    o[0] = fast_tanh(fmaf(accx, invH, b.x));
    o[1] = fast_tanh(fmaf(accy, invH, b.y));
    __builtin_nontemporal_store(o, &reinterpret_cast<f32x2*>(out)[(size_t)v * 64 + lane]);
}

extern "C" void kernel_launch(void* const* d_in, const int* in_sizes, int n_in,
                              void* d_out, int out_size, void* d_ws, size_t ws_size,
                              hipStream_t stream) {
    const float* x     = (const float*)d_in[0];
    const float* W     = (const float*)d_in[1];
    const float* a_src = (const float*)d_in[2];
    const float* a_dst = (const float*)d_in[3];
    const float* bias  = (const float*)d_in[4];
    const int*   ei    = (const int*)d_in[5];

    const int n = in_sizes[0] / IN_DIM;        // 100000
    const int E = in_sizes[5] / 2;             // 1000000
    const int nb = (n + BKT - 1) / BKT;        // 98

    float* ws = (float*)d_ws;
    size_t off = 0;
    unsigned short* h_bf = (unsigned short*)(ws + off); off += (size_t)n * HC / 2;
    float* alpha_s = ws + off; off += (size_t)n * NHEAD;
    float* alpha_d = ws + off; off += (size_t)n * NHEAD;
    unsigned short* w_hi = (unsigned short*)(ws + off); off += 16384;
    int* ibase        = (int*)(ws + off);
    int* deg          = ibase;                        // n
    int* row_start    = ibase + n;                    // n
    int* bucket_cnt   = ibase + 2 * (size_t)n;        // NBMAX
    int* bucket_base  = bucket_cnt + NBMAX;           // NBMAX+1
    int* bucket_cursor= bucket_base + NBMAX + 1;      // NBMAX
    unsigned* bucket_data = (unsigned*)(bucket_cursor + NBMAX);  // E
    int* csr_src      = (int*)(bucket_data + E);      // E

    float* out = (float*)d_out;

    const int nblkE = (E + BE - 1) / BE;              // 245

    hipMemsetAsync(bucket_cnt, 0, NBMAX * sizeof(int), stream);

    pack_hist_kernel<<<PACKB + nblkE, 256, 0, stream>>>(W, w_hi, ei, bucket_cnt, E, nb);
    bucket_scan_kernel<<<1, 128, 0, stream>>>(bucket_cnt, bucket_base, bucket_cursor, nb);
    scatter_gemm_kernel<<<nblkE + NGEMM, 512, 0, stream>>>(ei, bucket_cursor, bucket_data,
                                                           E, nb, nblkE,
                                                           x, w_hi, a_src, a_dst,
                                                           h_bf, alpha_s, alpha_d, n);
    bucket_build_kernel<<<nb, 1024, 0, stream>>>(bucket_base, bucket_data,
                                                 deg, row_start, csr_src, n);

    gather_kernel<<<(n + 3) / 4, 256, 0, stream>>>(row_start, deg, csr_src,
                                                   alpha_s, alpha_d, h_bf, bias, out, n);
}

// Round 18
// 132.003 us; speedup vs baseline: 1.0968x; 1.0968x over previous
//
#include <hip/hip_runtime.h>

#define IN_DIM 256
#define HC     128   // H*C
#define NHEAD  4
#define NEG    0.2f
#define BKT    1024  // dsts per bucket
#define NBMAX  128   // max buckets (n <= 131072)
#define EPT2   8     // edges per thread (fused 512-thr scatter)
#define BE     4096  // edges per block
#define PACKB  16    // pack_w blocks in fused K1

typedef __attribute__((ext_vector_type(8))) short short8v;
typedef __attribute__((ext_vector_type(4))) float f32x4;
typedef __attribute__((ext_vector_type(2))) float f32x2;
typedef __attribute__((ext_vector_type(4))) unsigned short ushort4v;

__device__ __forceinline__ unsigned short bf16_rn(float f) {
    unsigned u = __builtin_bit_cast(unsigned, f);
    return (unsigned short)((u + 0x7fffu + ((u >> 16) & 1u)) >> 16);
}
__device__ __forceinline__ float bf16_lo(unsigned v) {
    return __builtin_bit_cast(float, v << 16);
}
__device__ __forceinline__ float bf16_hi(unsigned v) {
    return __builtin_bit_cast(float, v & 0xffff0000u);
}
__device__ __forceinline__ float fast_tanh(float x) {
    float t = __expf(2.f * x);
    return fmaf(-2.f, __builtin_amdgcn_rcpf(t + 1.f), 1.f);
}
__device__ __forceinline__ float lrelu(float e) {
    return fmaxf(e, NEG * e);
}

// ---------------- K1: pack W (blocks 0..15)  ||  bucket histogram (rest) ----------------
__global__ __launch_bounds__(256) void pack_hist_kernel(const float* __restrict__ W,
                                                        unsigned short* __restrict__ w_hi,
                                                        const int* __restrict__ ei,
                                                        int* __restrict__ bucket_cnt,
                                                        int E, int nb) {
    __shared__ int lh[NBMAX];
    int tid = threadIdx.x;
    if (blockIdx.x < PACKB) {
        int t = blockIdx.x * 256 + tid;
        int l  = t & 63;
        int ct = (t >> 6) & 7;
        int s  = t >> 9;
        int kbase = s * 32 + (l >> 4) * 8;
        int col   = ct * 16 + (l & 15);
        size_t base = (size_t)t * 8;
#pragma unroll
        for (int e = 0; e < 8; ++e)
            w_hi[base + e] = bf16_rn(W[(size_t)(kbase + e) * HC + col]);
        return;
    }
    if (tid < NBMAX) lh[tid] = 0;
    __syncthreads();
    int base = (blockIdx.x - PACKB) * BE;
#pragma unroll
    for (int i = 0; i < 16; ++i) {
        int e = base + i * 256 + tid;
        if (e < E) atomicAdd(&lh[ei[E + e] >> 10], 1);
    }
    __syncthreads();
    if (tid < nb && lh[tid]) atomicAdd(&bucket_cnt[tid], lh[tid]);
}

// ---------------- K2: exclusive scan of bucket counts ----------------
__global__ __launch_bounds__(128) void bucket_scan_kernel(const int* __restrict__ bucket_cnt,
                                                          int* __restrict__ bucket_base,
                                                          int* __restrict__ bucket_cursor,
                                                          int nb) {
    __shared__ int ws0[1];
    int t = threadIdx.x;
    int v = (t < nb) ? bucket_cnt[t] : 0;
    int lane = t & 63, wd = t >> 6;
    int x = v;
#pragma unroll
    for (int off = 1; off < 64; off <<= 1) {
        int y = __shfl_up(x, off);
        if (lane >= off) x += y;
    }
    if (wd == 0 && lane == 63) ws0[0] = x;
    __syncthreads();
    int wo = wd ? ws0[0] : 0;
    int excl = wo + x - v;
    if (t < nb) { bucket_base[t] = excl; bucket_cursor[t] = excl; }
    if (t == 127) bucket_base[nb] = wo + x;   // total = E
}

// ---------------- K3: bucket scatter (blocks 0..nblkE-1)  ||  GEMM (rest) -------------
union KSmem {
    struct {
        unsigned short s_bf[64 * 256];   // 32 KB swizzled A tile
        float pS[64][4];
        float pD[64][4];
    } g;
    struct {
        int lh[NBMAX];
        int lofs[NBMAX];
        int gofs[NBMAX];
        int ws0;
        unsigned buf[BE];                // 16 KB
    } s;
};

__global__ __launch_bounds__(512) void scatter_gemm_kernel(const int* __restrict__ ei,
                                                           int* __restrict__ bucket_cursor,
                                                           unsigned* __restrict__ bucket_data,
                                                           int E, int nb, int nblkE,
                                                           const float* __restrict__ x,
                                                           const unsigned short* __restrict__ w_hi,
                                                           const float* __restrict__ a_src,
                                                           const float* __restrict__ a_dst,
                                                           unsigned short* __restrict__ h_bf,
                                                           float* __restrict__ alpha_s,
                                                           float* __restrict__ alpha_d, int n) {
    __shared__ KSmem sm;
    const int tid = threadIdx.x;

    if ((int)blockIdx.x < nblkE) {
        // ---------------- scatter path (512 threads, EPT2=8) ----------------
        if (tid < NBMAX) sm.s.lh[tid] = 0;
        __syncthreads();

        int base = blockIdx.x * BE;
        int bb[EPT2]; unsigned wv[EPT2]; int rr[EPT2];
#pragma unroll
        for (int i = 0; i < EPT2; ++i) {
            int e = base + i * 512 + tid;
            if (e < E) {
                int src = ei[e];
                int dst = ei[E + e];
                bb[i] = dst >> 10;
                wv[i] = (unsigned)src | ((unsigned)(dst & 1023) << 17);
                rr[i] = atomicAdd(&sm.s.lh[bb[i]], 1);
            } else bb[i] = -1;
        }
        __syncthreads();

        int lane = tid & 63, wd = tid >> 6;
        int v_ = 0, x_ = 0;
        if (tid < NBMAX) {
            v_ = sm.s.lh[tid]; x_ = v_;
#pragma unroll
            for (int off = 1; off < 64; off <<= 1) {
                int y = __shfl_up(x_, off);
                if (lane >= off) x_ += y;
            }
            if (wd == 0 && lane == 63) sm.s.ws0 = x_;
        }
        __syncthreads();
        if (tid < NBMAX) {
            int wo = wd ? sm.s.ws0 : 0;
            sm.s.lofs[tid] = wo + x_ - v_;
        }
        __syncthreads();

#pragma unroll
        for (int i = 0; i < EPT2; ++i)
            if (bb[i] >= 0) sm.s.buf[sm.s.lofs[bb[i]] + rr[i]] = wv[i];
        if (tid < nb) sm.s.gofs[tid] = sm.s.lh[tid] ? atomicAdd(&bucket_cursor[tid], sm.s.lh[tid]) : 0;
        __syncthreads();

        int wid = tid >> 6;
        for (int bk = wid; bk < nb; bk += 8) {
            int lo = sm.s.lofs[bk], cnt = sm.s.lh[bk], g = sm.s.gofs[bk];
            for (int j = lane; j < cnt; j += 64)
                bucket_data[g + j] = sm.s.buf[lo + j];
        }
        return;
    }

    // ---------------- GEMM path ----------------
    const int l   = tid & 63;
    const int wv_ = tid >> 6;
    const int row0 = ((int)blockIdx.x - nblkE) * 64;

    const float4* x4 = reinterpret_cast<const float4*>(x);
#pragma unroll
    for (int i = 0; i < 8; ++i) {
        int row = i * 8 + wv_;
        int c4  = l;
        float4 v = make_float4(0.f, 0.f, 0.f, 0.f);
        if (row0 + row < n) v = x4[(size_t)(row0 + row) * 64 + c4];
        ushort4v b;
        b[0] = bf16_rn(v.x); b[1] = bf16_rn(v.y);
        b[2] = bf16_rn(v.z); b[3] = bf16_rn(v.w);
        int slot = (c4 >> 1) ^ (row & 7);
        int uidx = row * 256 + (slot << 3) + ((c4 & 1) << 2);
        *reinterpret_cast<ushort4v*>(&sm.g.s_bf[uidx]) = b;
    }
    __syncthreads();

    const int ct_g = wv_ & 3;
    const int rt_g = wv_ >> 2;
    const int rrow = l & 15;
    const int kq   = l >> 4;

    f32x4 acc[2][2];
#pragma unroll
    for (int a = 0; a < 2; ++a)
#pragma unroll
        for (int b = 0; b < 2; ++b) acc[a][b] = (f32x4){0.f, 0.f, 0.f, 0.f};

    for (int s = 0; s < 8; ++s) {
        short8v bh[2];
#pragma unroll
        for (int c = 0; c < 2; ++c) {
            int ct = ct_g * 2 + c;
            bh[c] = *reinterpret_cast<const short8v*>(w_hi + ((size_t)(s * 8 + ct) * 64 + l) * 8);
        }
#pragma unroll
        for (int r = 0; r < 2; ++r) {
            int arow = rt_g * 32 + r * 16 + rrow;
            int c16  = kq + s * 4;
            int uidx = arow * 256 + ((c16 ^ (arow & 7)) << 3);
            short8v ah = *reinterpret_cast<const short8v*>(&sm.g.s_bf[uidx]);
#pragma unroll
            for (int c = 0; c < 2; ++c)
                acc[r][c] = __builtin_amdgcn_mfma_f32_16x16x32_bf16(ah, bh[c], acc[r][c], 0, 0, 0);
        }
    }

#pragma unroll
    for (int r = 0; r < 2; ++r) {
#pragma unroll
        for (int c = 0; c < 2; ++c) {
            int col = (ct_g * 2 + c) * 16 + (l & 15);
#pragma unroll
            for (int q = 0; q < 4; ++q) {
                int row = row0 + rt_g * 32 + r * 16 + (l >> 4) * 4 + q;
                if (row < n) h_bf[(size_t)row * HC + col] = bf16_rn(acc[r][c][q]);
            }
        }
    }

    float asc[2], adc[2];
#pragma unroll
    for (int c = 0; c < 2; ++c) {
        int col = (ct_g * 2 + c) * 16 + (l & 15);
        asc[c] = a_src[col];
        adc[c] = a_dst[col];
    }
#pragma unroll
    for (int r = 0; r < 2; ++r) {
#pragma unroll
        for (int q = 0; q < 4; ++q) {
            float vS = acc[r][0][q] * asc[0] + acc[r][1][q] * asc[1];
            float vD = acc[r][0][q] * adc[0] + acc[r][1][q] * adc[1];
#pragma unroll
            for (int m = 1; m < 16; m <<= 1) {
                vS += __shfl_xor(vS, m);
                vD += __shfl_xor(vD, m);
            }
            if ((l & 15) == 0) {
                int rl = rt_g * 32 + r * 16 + (l >> 4) * 4 + q;
                sm.g.pS[rl][ct_g] = vS;
                sm.g.pD[rl][ct_g] = vD;
            }
        }
    }
    __syncthreads();
    if (tid < 256) {
        int rl = tid >> 2, h = tid & 3;
        int row = row0 + rl;
        if (row < n) {
            alpha_s[(size_t)row * 4 + h] = sm.g.pS[rl][h];
            alpha_d[(size_t)row * 4 + h] = sm.g.pD[rl][h];
        }
    }
}

// ---------------- K4: per-bucket CSR finalize (LDS atomics only) ----------------
__global__ __launch_bounds__(1024) void bucket_build_kernel(const int* __restrict__ bucket_base,
                                                            const unsigned* __restrict__ bucket_data,
                                                            int* __restrict__ deg,
                                                            int* __restrict__ row_start,
                                                            int* __restrict__ csr_src, int n) {
    __shared__ int lc[BKT];
    __shared__ int sc[BKT];
    __shared__ int wsum[16];

    int b = blockIdx.x;
    int base = bucket_base[b];
    int end  = bucket_base[b + 1];
    int t = threadIdx.x;

    lc[t] = 0;
    __syncthreads();
    for (int i = base + t; i < end; i += 1024)
        atomicAdd(&lc[bucket_data[i] >> 17], 1);
    __syncthreads();

    int val = lc[t];
    int lane = t & 63, wd = t >> 6;
    int x = val;
#pragma unroll
    for (int off = 1; off < 64; off <<= 1) {
        int y = __shfl_up(x, off);
        if (lane >= off) x += y;
    }
    if (lane == 63) wsum[wd] = x;
    __syncthreads();
    if (wd == 0 && lane < 16) {
        int y = wsum[lane];
#pragma unroll
        for (int off = 1; off < 16; off <<= 1) {
            int z = __shfl_up(y, off);
            if (lane >= off) y += z;
        }
        wsum[lane] = y;
    }
    __syncthreads();
    int wo = wd ? wsum[wd - 1] : 0;
    int excl = wo + x - val;
    sc[t] = excl;
    int v = b * BKT + t;
    if (v < n) { deg[v] = val; row_start[v] = base + excl; }
    lc[t] = 0;
    __syncthreads();

    for (int i = base + t; i < end; i += 1024) {
        unsigned w = bucket_data[i];
        int d = w >> 17;
        int src = (int)(w & 0x1FFFFu);
        int p = atomicAdd(&lc[d], 1);
        csr_src[base + sc[d] + p] = src;
    }
}

// ---------------- K5: gather — cooperative-load single-pass softmax+PV+tanh ----------
__global__ __launch_bounds__(256, 4) void gather_kernel(const int* __restrict__ row_start,
                                                        const int* __restrict__ deg,
                                                        const int* __restrict__ csr_src,
                                                        const float* __restrict__ alpha_s,
                                                        const float* __restrict__ alpha_d,
                                                        const unsigned short* __restrict__ h_bf,
                                                        const float* __restrict__ bias,
                                                        float* __restrict__ out, int n) {
    int lane = threadIdx.x & 63;
    int wid  = threadIdx.x >> 6;
    int v = blockIdx.x * 4 + wid;
    if (v >= n) return;
    int start = row_start[v];
    int cnt = deg[v];
    int head = lane >> 4;   // output head
    int hc   = lane & 3;    // cooperative head

    const unsigned* hb = reinterpret_cast<const unsigned*>(h_bf);

    float adC = alpha_d[(size_t)v * 4 + hc];
    float asC = alpha_s[(size_t)v * 4 + hc];
    float adH = __shfl(adC, head);
    float asH = __shfl(asC, head);
    float pself = __expf(lrelu(asH + adH));
    unsigned hv0 = hb[((unsigned)v << 6) + lane];
    float s = pself;
    float accx = pself * bf16_lo(hv0);
    float accy = pself * bf16_hi(hv0);

    int j = 0;
    for (; j + 8 <= cnt; j += 8) {
        int cv = csr_src[start + j + (lane & 7)];
        int sj = __shfl(cv, lane >> 2);
        float av = alpha_s[(size_t)sj * 4 + hc];
        float w  = __expf(lrelu(av + adC));
#pragma unroll
        for (int k = 0; k < 8; ++k) {
            int sk   = __shfl(cv, k);
            float wk = __shfl(w, (k << 2) | head);
            unsigned hk = hb[((unsigned)sk << 6) + lane];
            s += wk;
            accx = fmaf(wk, bf16_lo(hk), accx);
            accy = fmaf(wk, bf16_hi(hk), accy);
        }
    }
    if (j + 4 <= cnt) {
        int cv = csr_src[start + j + (lane & 3)];
        int sj = __shfl(cv, lane >> 2);
        float av = alpha_s[(size_t)sj * 4 + hc];
        float w  = __expf(lrelu(av + adC));
#pragma unroll
        for (int k = 0; k < 4; ++k) {
            int sk   = __shfl(cv, k);
            float wk = __shfl(w, (k << 2) | head);
            unsigned hk = hb[((unsigned)sk << 6) + lane];
            s += wk;
            accx = fmaf(wk, bf16_lo(hk), accx);
            accy = fmaf(wk, bf16_hi(hk), accy);
        }
        j += 4;
    }
    for (; j < cnt; ++j) {
        int s0 = csr_src[start + j];
        float a0 = alpha_s[(size_t)s0 * 4 + head];
        unsigned h0 = hb[((unsigned)s0 << 6) + lane];
        float w0 = __expf(lrelu(a0 + adH));
        s += w0;
        accx = fmaf(w0, bf16_lo(h0), accx);
        accy = fmaf(w0, bf16_hi(h0), accy);
    }

    float invH = __builtin_amdgcn_rcpf(s + 1e-16f);
    float2 b = reinterpret_cast<const float2*>(bias)[lane];
    f32x2 o;
    o[0] = fast_tanh(fmaf(accx, invH, b.x));
    o[1] = fast_tanh(fmaf(accy, invH, b.y));
    __builtin_nontemporal_store(o, &reinterpret_cast<f32x2*>(out)[(size_t)v * 64 + lane]);
}

extern "C" void kernel_launch(void* const* d_in, const int* in_sizes, int n_in,
                              void* d_out, int out_size, void* d_ws, size_t ws_size,
                              hipStream_t stream) {
    const float* x     = (const float*)d_in[0];
    const float* W     = (const float*)d_in[1];
    const float* a_src = (const float*)d_in[2];
    const float* a_dst = (const float*)d_in[3];
    const float* bias  = (const float*)d_in[4];
    const int*   ei    = (const int*)d_in[5];

    const int n = in_sizes[0] / IN_DIM;        // 100000
    const int E = in_sizes[5] / 2;             // 1000000
    const int nb = (n + BKT - 1) / BKT;        // 98

    float* ws = (float*)d_ws;
    size_t off = 0;
    unsigned short* h_bf = (unsigned short*)(ws + off); off += (size_t)n * HC / 2;
    float* alpha_s = ws + off; off += (size_t)n * NHEAD;
    float* alpha_d = ws + off; off += (size_t)n * NHEAD;
    unsigned short* w_hi = (unsigned short*)(ws + off); off += 16384;
    int* ibase        = (int*)(ws + off);
    int* deg          = ibase;                        // n
    int* row_start    = ibase + n;                    // n
    int* bucket_cnt   = ibase + 2 * (size_t)n;        // NBMAX
    int* bucket_base  = bucket_cnt + NBMAX;           // NBMAX+1
    int* bucket_cursor= bucket_base + NBMAX + 1;      // NBMAX
    unsigned* bucket_data = (unsigned*)(bucket_cursor + NBMAX);  // E
    int* csr_src      = (int*)(bucket_data + E);      // E

    float* out = (float*)d_out;

    const int nblkE = (E + BE - 1) / BE;              // 245
    const int gemmB = (n + 63) / 64;                  // 1563

    hipMemsetAsync(bucket_cnt, 0, NBMAX * sizeof(int), stream);

    pack_hist_kernel<<<PACKB + nblkE, 256, 0, stream>>>(W, w_hi, ei, bucket_cnt, E, nb);
    bucket_scan_kernel<<<1, 128, 0, stream>>>(bucket_cnt, bucket_base, bucket_cursor, nb);
    scatter_gemm_kernel<<<nblkE + gemmB, 512, 0, stream>>>(ei, bucket_cursor, bucket_data,
                                                           E, nb, nblkE,
                                                           x, w_hi, a_src, a_dst,
                                                           h_bf, alpha_s, alpha_d, n);
    bucket_build_kernel<<<nb, 1024, 0, stream>>>(bucket_base, bucket_data,
                                                 deg, row_start, csr_src, n);

    gather_kernel<<<(n + 3) / 4, 256, 0, stream>>>(row_start, deg, csr_src,
                                                   alpha_s, alpha_d, h_bf, bias, out, n);
}